// Round 1
// 262.558 us; speedup vs baseline: 1.0258x; 1.0258x over previous
//
#include <hip/hip_runtime.h>
#include <hip/hip_bf16.h>

typedef unsigned short u16;
typedef __attribute__((ext_vector_type(8))) short bf16x8;
typedef __attribute__((ext_vector_type(4))) float f32x4;

#define MFMA16(a, b, c) __builtin_amdgcn_mfma_f32_16x16x32_bf16((a), (b), (c), 0, 0, 0)

__device__ __forceinline__ u16 f2bf(float f) {
  union { float f; unsigned u; } v; v.f = f;
  unsigned r = v.u + 0x7fffu + ((v.u >> 16) & 1u);  // RNE
  return (u16)(r >> 16);
}

// pack two fp32 -> dword of 2 bf16 by truncation (1 VALU op)
__device__ __forceinline__ unsigned pk_trunc(float hi, float lo) {
  union { float f; unsigned u; } a, b; a.f = hi; b.f = lo;
  return __builtin_amdgcn_perm(a.u, b.u, 0x07060302u);
}

__device__ __forceinline__ void gload_lds16(const u16* g, u16* l) {
  __builtin_amdgcn_global_load_lds((const __attribute__((address_space(1))) void*)g,
                                   (__attribute__((address_space(3))) void*)l, 16, 0, 0);
}

// ---------------- fp32 -> bf16 convert: 8 elems/thread ----------------
__global__ __launch_bounds__(256) void convert_bf16_k(const float* __restrict__ in,
                                                      u16* __restrict__ out, int n) {
  int i = (blockIdx.x * 256 + threadIdx.x) * 8;
  if (i >= n) return;
  float4 v0 = *(const float4*)(in + i);
  float4 v1 = *(const float4*)(in + i + 4);
  uint4 o;
  o.x = (unsigned)f2bf(v0.x) | ((unsigned)f2bf(v0.y) << 16);
  o.y = (unsigned)f2bf(v0.z) | ((unsigned)f2bf(v0.w) << 16);
  o.z = (unsigned)f2bf(v1.x) | ((unsigned)f2bf(v1.y) << 16);
  o.w = (unsigned)f2bf(v1.z) | ((unsigned)f2bf(v1.w) << 16);
  *(uint4*)(out + i) = o;
}

// ---------------- fused transposes: Wa [1024][3072] and Wp [1024][1024] -> bf16 [N][K] ----------------
__global__ __launch_bounds__(256) void transpose2_k(const float* __restrict__ Wa, u16* __restrict__ WaT,
                                                    const float* __restrict__ Wp, u16* __restrict__ WpT) {
  __shared__ float tile[64][65];
  int b = blockIdx.x;
  const float* W; u16* Wt; int N, n0, k0;
  if (b < 768) { W = Wa; Wt = WaT; N = 3072; n0 = (b % 48) * 64; k0 = (b / 48) * 64; }
  else { int c = b - 768; W = Wp; Wt = WpT; N = 1024; n0 = (c & 15) * 64; k0 = (c >> 4) * 64; }
  const int tx = threadIdx.x & 63, ty = threadIdx.x >> 6;
#pragma unroll
  for (int i = 0; i < 16; ++i)
    tile[ty + 4 * i][tx] = W[(size_t)(k0 + ty + 4 * i) * N + n0 + tx];
  __syncthreads();
#pragma unroll
  for (int i = 0; i < 16; ++i)
    Wt[(size_t)(n0 + ty + 4 * i) * 1024 + k0 + tx] = f2bf(tile[tx][ty + 4 * i]);
}

// ---------------- GEMM building blocks: 128x128 tile, BK=32, m97-style (kept for gemm_proj) ----------------
#define GEMM_PROLOG                                                                \
  __shared__ u16 As[128 * 32];                                                     \
  __shared__ u16 Bs[128 * 32];                                                     \
  const int tid = threadIdx.x;                                                     \
  const int w = tid >> 6, lane = tid & 63;                                         \
  const int wm = w & 1, wn = w >> 1;                                               \
  const int fr = lane & 15, fg = lane >> 4;                                        \
  const int srow = lane >> 2, skof = (lane & 3) * 8;                               \
  u16* lA = As + w * 1024;                                                         \
  u16* lB = Bs + w * 1024;                                                         \
  f32x4 acc[4][4];                                                                 \
  _Pragma("unroll") for (int i = 0; i < 4; i++)                                    \
      _Pragma("unroll") for (int j = 0; j < 4; j++) acc[i][j] = (f32x4){0, 0, 0, 0};

// SWAP=1: acc = bfr x af (C^T: col=t, regs=4 consecutive n). SWAP=0: classic.
#define GEMM_KLOOP(Aptr, Btptr, SWAP)                                              \
  {                                                                                \
    const u16* gA0 = (Aptr) + (size_t)(m0 + w * 32 + srow) * 1024 + skof;          \
    const u16* gB0 = (Btptr) + (size_t)(n0 + w * 32 + srow) * 1024 + skof;         \
    for (int kt = 0; kt < 32; ++kt) {                                              \
      const int ko = kt * 32;                                                      \
      gload_lds16(gA0 + ko, lA);                                                   \
      gload_lds16(gA0 + ko + 16 * 1024, lA + 512);                                 \
      gload_lds16(gB0 + ko, lB);                                                   \
      gload_lds16(gB0 + ko + 16 * 1024, lB + 512);                                 \
      __syncthreads();                                                             \
      bf16x8 af[4], bfr[4];                                                        \
      _Pragma("unroll") for (int mb = 0; mb < 4; ++mb)                             \
          af[mb] = *(const bf16x8*)&As[(wm * 64 + mb * 16 + fr) * 32 + fg * 8];    \
      _Pragma("unroll") for (int nb = 0; nb < 4; ++nb)                             \
          bfr[nb] = *(const bf16x8*)&Bs[(wn * 64 + nb * 16 + fr) * 32 + fg * 8];   \
      _Pragma("unroll") for (int mb = 0; mb < 4; ++mb)                             \
          _Pragma("unroll") for (int nb = 0; nb < 4; ++nb)                         \
              acc[mb][nb] = (SWAP) ? MFMA16(bfr[nb], af[mb], acc[mb][nb])          \
                                   : MFMA16(af[mb], bfr[nb], acc[mb][nb]);         \
      __syncthreads();                                                             \
    }                                                                              \
  }

// ---------------- QKV GEMM: 256x256 tile, BK=64, 8-phase counted-vmcnt schedule ----------------
// T2 st_16x32 swizzle (pre-swizzled global src + swizzled ds_read), T3+T4 phases,
// T5 setprio, T1 XCD swizzle. LDS 128 KiB (2 buf x {A,B} x 256x64 bf16), 8 waves.
#define BAR() asm volatile("s_barrier" ::: "memory")
#define WLG()                                                   \
  do {                                                          \
    asm volatile("s_waitcnt lgkmcnt(0)" ::: "memory");          \
    __builtin_amdgcn_sched_barrier(0);                          \
  } while (0)

__global__ __launch_bounds__(512, 2) void gemm_qkv_8p(const u16* __restrict__ A,
                                                      const u16* __restrict__ Bt,
                                                      const float* __restrict__ bias,
                                                      u16* __restrict__ Qo, u16* __restrict__ Ko,
                                                      u16* __restrict__ Vt) {
  __shared__ u16 sm[2][2][16384];  // [buf][A=0/B=1][32KB as u16]
  const int bid = blockIdx.x;
  const int swz = (bid & 7) * 48 + (bid >> 3);        // 384 % 8 == 0 -> bijective
  const int m0 = (swz / 12) * 256, n0 = (swz % 12) * 256;
  const int tid = threadIdx.x, w = tid >> 6, lane = tid & 63;
  const int wm = w >> 2, wn = w & 3;                  // 2M x 4N waves, 128x64 out each
  const int fr = lane & 15, fg = lane >> 4;

  // staging source coords (inverse st_16x32 swizzle folded into the global address)
  const int sr = lane >> 2;
  const int sk = (lane & 1) * 8 + ((((lane >> 1) ^ (lane >> 5)) & 1) << 4);
  const int kc = (w & 1) * 32 + sk;
  const int r0 = (w >> 1) * 16 + sr;
  // swizzled ds_read lane offset (u16 units): row fr, col fg*8 within a 16x32 subtile
  const int lsw = fr * 32 + ((fg * 8) ^ ((fr & 8) ? 16 : 0));

  const u16* gA00 = A + (size_t)(m0 + r0) * 1024 + kc;
  const u16* gB00 = Bt + (size_t)(n0 + r0) * 1024 + kc;

// stage one 8KB slice: half h (128 rows), call c (64 rows), tile tt -> buf tt&1
#define STG_(mat, base, tt, h, c)                                                    \
  gload_lds16((base) + (size_t)(h) * 131072 + (c) * 65536 + (size_t)(tt) * 64,       \
              &sm[(tt) & 1][mat][(h) * 8192 + (c) * 4096 + w * 512])

  f32x4 acc[8][4];
#pragma unroll
  for (int i = 0; i < 8; ++i)
#pragma unroll
    for (int j = 0; j < 4; ++j) acc[i][j] = (f32x4){0, 0, 0, 0};

  // prologue: tile0 full (8 loads/wave) + B-half0(1) (2 loads/wave); retire tile0, keep 2 in flight
  STG_(0, gA00, 0, 0, 0); STG_(0, gA00, 0, 0, 1);
  STG_(0, gA00, 0, 1, 0); STG_(0, gA00, 0, 1, 1);
  STG_(1, gB00, 0, 0, 0); STG_(1, gB00, 0, 0, 1);
  STG_(1, gB00, 0, 1, 0); STG_(1, gB00, 0, 1, 1);
  STG_(1, gB00, 1, 0, 0); STG_(1, gB00, 1, 0, 1);
  asm volatile("s_waitcnt vmcnt(2)" ::: "memory");
  BAR();

#define LDA4(KK, MB0)                                                     \
  _Pragma("unroll") for (int i = 0; i < 4; ++i)                           \
      av[i] = *(const bf16x8*)(ard + ((MB0 + i) * 2 + (KK)) * 512);
#define LDB4(KK)                                                          \
  _Pragma("unroll") for (int i = 0; i < 4; ++i)                           \
      bv[i] = *(const bf16x8*)(brd + (i * 2 + (KK)) * 512);
#define MM16(MB0)                                                         \
  __builtin_amdgcn_s_setprio(1);                                          \
  _Pragma("unroll") for (int i = 0; i < 4; ++i)                           \
      _Pragma("unroll") for (int j = 0; j < 4; ++j)                       \
          acc[MB0 + i][j] = MFMA16(av[i], bv[j], acc[MB0 + i][j]);        \
  __builtin_amdgcn_s_setprio(0);

  for (int t = 0; t < 16; ++t) {
    const int b = t & 1;
    const u16* ard = &sm[b][0][wm * 8192 + lsw];
    const u16* brd = &sm[b][1][(wn >> 1) * 8192 + (wn & 1) * 4096 + lsw];
    bf16x8 av[4], bv[4];

    // P1: A(mb0-3,kk0) + B(kk0); stage B-half1(t+1)  [dest buf b^1, dead since t-1/P3]
    LDA4(0, 0); LDB4(0);
    if (t + 1 < 16) { STG_(1, gB00, t + 1, 1, 0); STG_(1, gB00, t + 1, 1, 1); }
    BAR(); WLG(); MM16(0); BAR();

    // P2: A(mb4-7,kk0); stage A-half0(t+1)  [dest buf b^1, dead since t-1/P4]
    LDA4(0, 4);
    if (t + 1 < 16) { STG_(0, gA00, t + 1, 0, 0); STG_(0, gA00, t + 1, 0, 1); }
    BAR(); WLG(); MM16(4); BAR();

    // P3: A(mb0-3,kk1) + B(kk1); stage A-half1(t+1)
    LDA4(1, 0); LDB4(1);
    if (t + 1 < 16) { STG_(0, gA00, t + 1, 1, 0); STG_(0, gA00, t + 1, 1, 1); }
    BAR(); WLG(); MM16(0); BAR();

    // P4: A(mb4-7,kk1); stage B-half0(t+2)  [dest buf b B-slot, B(t) reads done at P3-end barrier]
    LDA4(1, 4);
    if (t + 2 < 16) { STG_(1, gB00, t + 2, 0, 0); STG_(1, gB00, t + 2, 0, 1); }
    BAR(); WLG(); MM16(4);
    // counted drain: everything tile t+1 needs is older than P4's 2 loads
    if (t + 2 < 16)      asm volatile("s_waitcnt vmcnt(2)" ::: "memory");
    else if (t + 1 < 16) asm volatile("s_waitcnt vmcnt(0)" ::: "memory");
    BAR();
  }

  // epilogue: identical scatter semantics to the previous gemm_qkv, 8 mb blocks
  const int which = n0 >> 10;  // block-uniform: 0=Q, 1=K, 2=V
#pragma unroll
  for (int nb = 0; nb < 4; ++nb) {
    const int n = n0 + wn * 64 + nb * 16 + fr;
    const float bs = bias[n];
    const int c = n & 1023, h = c >> 6, hd = c & 63;
#pragma unroll
    for (int mb = 0; mb < 8; ++mb) {
      const int mbase = m0 + wm * 128 + mb * 16 + fg * 4;
      const int bb = mbase >> 11;
      const int tt = mbase & 2047;
      if (which == 0) {
        u16* dst = Qo + ((size_t)(bb * 16 + h) * 2048 + tt) * 64 + hd;
#pragma unroll
        for (int r = 0; r < 4; ++r) dst[(size_t)r * 64] = f2bf((acc[mb][nb][r] + bs) * 0.125f);
      } else if (which == 1) {
        u16* dst = Ko + ((size_t)(bb * 16 + h) * 2048 + tt) * 64 + hd;
#pragma unroll
        for (int r = 0; r < 4; ++r) dst[(size_t)r * 64] = f2bf(acc[mb][nb][r] + bs);
      } else {
        ushort4 pv;
        pv.x = f2bf(acc[mb][nb][0] + bs);
        pv.y = f2bf(acc[mb][nb][1] + bs);
        pv.z = f2bf(acc[mb][nb][2] + bs);
        pv.w = f2bf(acc[mb][nb][3] + bs);
        *(ushort4*)(Vt + ((size_t)(bb * 16 + h) * 64 + hd) * 2048 + tt) = pv;
      }
    }
  }
}

// ---------------- Proj GEMM: swapped epilogue (float4 stores) ----------------
__global__ __launch_bounds__(256) void gemm_proj(const u16* __restrict__ A,
                                                 const u16* __restrict__ Bt,
                                                 const float* __restrict__ bias,
                                                 float* __restrict__ O) {
  const int id = blockIdx.x;
  const int m0 = (id >> 3) * 128, n0 = (id & 7) * 128;
  GEMM_PROLOG
  GEMM_KLOOP(A, Bt, 1)
#pragma unroll
  for (int mb = 0; mb < 4; ++mb) {
    const int tg = m0 + wm * 64 + mb * 16 + fr;
#pragma unroll
    for (int nb = 0; nb < 4; ++nb) {
      const int n = n0 + wn * 64 + nb * 16 + 4 * fg;
      const float4 b4 = *(const float4*)(bias + n);
      float4 o;
      o.x = acc[mb][nb][0] + b4.x;
      o.y = acc[mb][nb][1] + b4.y;
      o.z = acc[mb][nb][2] + b4.z;
      o.w = acc[mb][nb][3] + b4.w;
      *(float4*)(O + (size_t)tg * 1024 + n) = o;
    }
  }
}

// ---------------- Flash attention (R4/v4 form, measured best): 128 q/block (32/wave) ----------------
// S^T = K·Q^T (no max pass), O^T = V^T·P^T. PSTR=72 -> 36.9 KB LDS -> 4 blocks/CU.
#define PSTR 72
__global__ __launch_bounds__(256) void attn_k(const u16* __restrict__ Q,
                                              const u16* __restrict__ Kb,
                                              const u16* __restrict__ Vt,
                                              u16* __restrict__ Y) {
  __shared__ u16 Ks[64 * 72];
  __shared__ u16 Vs[64 * 72];
  __shared__ u16 Ps[4 * 32 * PSTR];
  const int L = blockIdx.x;
  const int xcd = L & 7, slot = L >> 3;
  const int bh = xcd * 8 + (slot & 7);
  const int qt = 15 - (slot >> 3);
  const int tid = threadIdx.x, w = tid >> 6, lane = tid & 63;
  const int fr = lane & 15, fg = lane >> 4;
  const u16* Qp = Q + (size_t)bh * 2048 * 64;
  const u16* Kp = Kb + (size_t)bh * 2048 * 64;
  const u16* Vp = Vt + (size_t)bh * 64 * 2048;
  const int qw = qt * 128 + w * 32;

  bf16x8 qa[2][2];
#pragma unroll
  for (int g = 0; g < 2; ++g)
#pragma unroll
    for (int c = 0; c < 2; ++c)
      qa[g][c] = *(const bf16x8*)(Qp + (size_t)(qw + g * 16 + fr) * 64 + c * 32 + fg * 8);

  float li[2] = {0.f, 0.f};
  f32x4 ot[2][4];
#pragma unroll
  for (int g = 0; g < 2; ++g)
#pragma unroll
    for (int mb = 0; mb < 4; ++mb) ot[g][mb] = (f32x4){0, 0, 0, 0};

  const int srow = tid >> 2, scol = (tid & 3) * 16;
  u16* Pw = Ps + w * 32 * PSTR;
  const int nk = 2 * qt + 2;
  const u16* Kg = Kp + (size_t)srow * 64 + scol;
  const u16* Vg = Vp + (size_t)srow * 2048 + scol;

  uint4 kr0 = *(const uint4*)(Kg);
  uint4 kr1 = *(const uint4*)(Kg + 8);
  uint4 vr0 = *(const uint4*)(Vg);
  uint4 vr1 = *(const uint4*)(Vg + 8);

  for (int jt = 0; jt < nk; ++jt) {
    const int k0 = jt * 64;
    if (jt) __syncthreads();
    *(uint4*)&Ks[srow * 72 + scol] = kr0;
    *(uint4*)&Ks[srow * 72 + scol + 8] = kr1;
    *(uint4*)&Vs[srow * 72 + scol] = vr0;
    *(uint4*)&Vs[srow * 72 + scol + 8] = vr1;
    __syncthreads();
    if (jt + 1 < nk) {
      const int kn = (jt + 1) * 64;
      kr0 = *(const uint4*)(Kg + (size_t)kn * 64);
      kr1 = *(const uint4*)(Kg + (size_t)kn * 64 + 8);
      vr0 = *(const uint4*)(Vg + kn);
      vr1 = *(const uint4*)(Vg + kn + 8);
    }
    if (k0 > qw + 31) continue;

    bf16x8 kb[4][2];
#pragma unroll
    for (int nb = 0; nb < 4; ++nb) {
      kb[nb][0] = *(const bf16x8*)&Ks[(nb * 16 + fr) * 72 + fg * 8];
      kb[nb][1] = *(const bf16x8*)&Ks[(nb * 16 + fr) * 72 + 32 + fg * 8];
    }
    f32x4 st[2][4];
#pragma unroll
    for (int g = 0; g < 2; ++g)
#pragma unroll
      for (int nb = 0; nb < 4; ++nb) {
        f32x4 z = (f32x4){0, 0, 0, 0};
        z = MFMA16(kb[nb][0], qa[g][0], z);
        z = MFMA16(kb[nb][1], qa[g][1], z);
        st[g][nb] = z;
      }
    const bool needmask = (k0 + 63 > qw);
#pragma unroll
    for (int g = 0; g < 2; ++g) {
      const int q = qw + g * 16 + fr;
      float rs0 = 0.f, rs1 = 0.f;
#pragma unroll
      for (int nb = 0; nb < 4; ++nb) {
        const int kcb = k0 + nb * 16 + 4 * fg;
        float p0 = __expf(st[g][nb][0]);
        float p1 = __expf(st[g][nb][1]);
        float p2 = __expf(st[g][nb][2]);
        float p3 = __expf(st[g][nb][3]);
        if (needmask) {
          p0 = (kcb + 0 > q) ? 0.f : p0;
          p1 = (kcb + 1 > q) ? 0.f : p1;
          p2 = (kcb + 2 > q) ? 0.f : p2;
          p3 = (kcb + 3 > q) ? 0.f : p3;
        }
        rs0 += p0 + p1;
        rs1 += p2 + p3;
        *(uint2*)&Pw[(g * 16 + fr) * PSTR + nb * 16 + 4 * fg] =
            make_uint2(pk_trunc(p1, p0), pk_trunc(p3, p2));
      }
      li[g] += rs0 + rs1;
    }
    bf16x8 pa[2][2];
#pragma unroll
    for (int g = 0; g < 2; ++g)
#pragma unroll
      for (int H = 0; H < 2; ++H)
        pa[g][H] = *(const bf16x8*)&Pw[(g * 16 + fr) * PSTR + H * 32 + fg * 8];
#pragma unroll
    for (int mb = 0; mb < 4; ++mb) {
      bf16x8 vb0 = *(const bf16x8*)&Vs[(mb * 16 + fr) * 72 + fg * 8];
      bf16x8 vb1 = *(const bf16x8*)&Vs[(mb * 16 + fr) * 72 + 32 + fg * 8];
#pragma unroll
      for (int g = 0; g < 2; ++g) {
        ot[g][mb] = MFMA16(vb0, pa[g][0], ot[g][mb]);
        ot[g][mb] = MFMA16(vb1, pa[g][1], ot[g][mb]);
      }
    }
  }

  const int b = bh >> 4, h = bh & 15;
#pragma unroll
  for (int g = 0; g < 2; ++g) {
    float l = li[g];
    l += __shfl_xor(l, 16);
    l += __shfl_xor(l, 32);
    const float inv = 1.0f / l;
    const int t = qw + g * 16 + fr;
    u16* yrow = Y + ((size_t)b * 2048 + t) * 1024 + h * 64;
#pragma unroll
    for (int mb = 0; mb < 4; ++mb) {
      const unsigned d0 = (unsigned)f2bf(ot[g][mb][0] * inv) |
                          ((unsigned)f2bf(ot[g][mb][1] * inv) << 16);
      const unsigned d1 = (unsigned)f2bf(ot[g][mb][2] * inv) |
                          ((unsigned)f2bf(ot[g][mb][3] * inv) << 16);
      *(uint2*)&yrow[mb * 16 + fg * 4] = make_uint2(d0, d1);
    }
  }
}

extern "C" void kernel_launch(void* const* d_in, const int* in_sizes, int n_in,
                              void* d_out, int out_size, void* d_ws, size_t ws_size,
                              hipStream_t stream) {
  const float* x = (const float*)d_in[0];
  const float* Wa = (const float*)d_in[1];
  const float* ba = (const float*)d_in[2];
  const float* Wp = (const float*)d_in[3];
  const float* bp = (const float*)d_in[4];
  float* out = (float*)d_out;

  char* p = (char*)d_ws;
  u16* xb = (u16*)p;   p += (size_t)8192 * 1024 * 2;
  u16* WaT = (u16*)p;  p += (size_t)3072 * 1024 * 2;
  u16* WpT = (u16*)p;  p += (size_t)1024 * 1024 * 2;
  u16* Qb = (u16*)p;   p += (size_t)64 * 2048 * 64 * 2;
  u16* Kbuf = (u16*)p; p += (size_t)64 * 2048 * 64 * 2;
  u16* Vtb = (u16*)p;  p += (size_t)64 * 64 * 2048 * 2;
  u16* Yb = (u16*)p;   p += (size_t)8192 * 1024 * 2;

  convert_bf16_k<<<4096, 256, 0, stream>>>(x, xb, 8192 * 1024);
  transpose2_k<<<1024, 256, 0, stream>>>(Wa, WaT, Wp, WpT);
  gemm_qkv_8p<<<384, 512, 0, stream>>>(xb, WaT, ba, Qb, Kbuf, Vtb);
  attn_k<<<1024, 256, 0, stream>>>(Qb, Kbuf, Vtb, Yb);
  gemm_proj<<<512, 256, 0, stream>>>(Yb, WpT, bp, out);
}

// Round 2
// 254.314 us; speedup vs baseline: 1.0590x; 1.0324x over previous
//
#include <hip/hip_runtime.h>
#include <hip/hip_bf16.h>

typedef unsigned short u16;
typedef __attribute__((ext_vector_type(8))) short bf16x8;
typedef __attribute__((ext_vector_type(4))) float f32x4;

#define MFMA16(a, b, c) __builtin_amdgcn_mfma_f32_16x16x32_bf16((a), (b), (c), 0, 0, 0)

__device__ __forceinline__ u16 f2bf(float f) {
  union { float f; unsigned u; } v; v.f = f;
  unsigned r = v.u + 0x7fffu + ((v.u >> 16) & 1u);  // RNE
  return (u16)(r >> 16);
}

// pack two fp32 -> dword of 2 bf16 by truncation (1 VALU op)
__device__ __forceinline__ unsigned pk_trunc(float hi, float lo) {
  union { float f; unsigned u; } a, b; a.f = hi; b.f = lo;
  return __builtin_amdgcn_perm(a.u, b.u, 0x07060302u);
}

__device__ __forceinline__ void gload_lds16(const u16* g, u16* l) {
  __builtin_amdgcn_global_load_lds((const __attribute__((address_space(1))) void*)g,
                                   (__attribute__((address_space(3))) void*)l, 16, 0, 0);
}

// ---------------- fp32 -> bf16 convert: 8 elems/thread ----------------
__global__ __launch_bounds__(256) void convert_bf16_k(const float* __restrict__ in,
                                                      u16* __restrict__ out, int n) {
  int i = (blockIdx.x * 256 + threadIdx.x) * 8;
  if (i >= n) return;
  float4 v0 = *(const float4*)(in + i);
  float4 v1 = *(const float4*)(in + i + 4);
  uint4 o;
  o.x = (unsigned)f2bf(v0.x) | ((unsigned)f2bf(v0.y) << 16);
  o.y = (unsigned)f2bf(v0.z) | ((unsigned)f2bf(v0.w) << 16);
  o.z = (unsigned)f2bf(v1.x) | ((unsigned)f2bf(v1.y) << 16);
  o.w = (unsigned)f2bf(v1.z) | ((unsigned)f2bf(v1.w) << 16);
  *(uint4*)(out + i) = o;
}

// ---------------- fused transposes: Wa [1024][3072] and Wp [1024][1024] -> bf16 [N][K] ----------------
__global__ __launch_bounds__(256) void transpose2_k(const float* __restrict__ Wa, u16* __restrict__ WaT,
                                                    const float* __restrict__ Wp, u16* __restrict__ WpT) {
  __shared__ float tile[64][65];
  int b = blockIdx.x;
  const float* W; u16* Wt; int N, n0, k0;
  if (b < 768) { W = Wa; Wt = WaT; N = 3072; n0 = (b % 48) * 64; k0 = (b / 48) * 64; }
  else { int c = b - 768; W = Wp; Wt = WpT; N = 1024; n0 = (c & 15) * 64; k0 = (c >> 4) * 64; }
  const int tx = threadIdx.x & 63, ty = threadIdx.x >> 6;
#pragma unroll
  for (int i = 0; i < 16; ++i)
    tile[ty + 4 * i][tx] = W[(size_t)(k0 + ty + 4 * i) * N + n0 + tx];
  __syncthreads();
#pragma unroll
  for (int i = 0; i < 16; ++i)
    Wt[(size_t)(n0 + ty + 4 * i) * 1024 + k0 + tx] = f2bf(tile[tx][ty + 4 * i]);
}

// ---------------- 8-phase 256-wide GEMM core (T1+T2+T3+T4+T5) ----------------
// 512 thr / 8 waves (2M x 4N). st_16x32 swizzle: linear gload_lds dest +
// inverse-swizzled global src + swizzled ds_read (rule 21). All t+1 stages
// issued in P1/P2 -> boundary vmcnt(0) has >=2 phases slack. Compile-time BUF.
#define BAR() asm volatile("s_barrier" ::: "memory")
#define WLG()                                                   \
  do {                                                          \
    asm volatile("s_waitcnt lgkmcnt(0)" ::: "memory");          \
    __builtin_amdgcn_sched_barrier(0);                          \
  } while (0)
#define VMW0() asm volatile("s_waitcnt vmcnt(0)" ::: "memory")

#define LANE_CONSTS                                                       \
  const int tid = threadIdx.x, w = tid >> 6, lane = tid & 63;             \
  const int wm = w >> 2, wn = w & 3;                                      \
  const int fr = lane & 15, fg = lane >> 4;                               \
  const int sr = lane >> 2;                                               \
  const int sk = (lane & 1) * 8 + ((((lane >> 1) ^ (lane >> 5)) & 1) << 4); \
  const int kc = (w & 1) * 32 + sk;                                       \
  const int r0g = (w >> 1) * 16 + sr;                                     \
  const int lsw = fr * 32 + ((fg * 8) ^ ((fr & 8) ? 16 : 0));

// ---------------- QKV GEMM: 256x256 tile, K=1024 (16 K-tiles of 64) ----------------
__global__ __launch_bounds__(512, 2) void gemm_qkv_8p(const u16* __restrict__ A,
                                                      const u16* __restrict__ Bt,
                                                      const float* __restrict__ bias,
                                                      u16* __restrict__ Qo, u16* __restrict__ Ko,
                                                      u16* __restrict__ Vt) {
  __shared__ u16 sm[2][32768];  // per buf: A [0,16384) u16, B [16384,32768)
  const int bid = blockIdx.x;
  const int swz = (bid & 7) * 48 + (bid >> 3);  // 384 % 8 == 0 -> bijective
  const int m0 = (swz / 12) * 256, n0 = (swz % 12) * 256;
  LANE_CONSTS
  const int aoff = wm * 8192 + lsw;
  const int boff = 16384 + (wn >> 1) * 8192 + (wn & 1) * 4096 + lsw;

  const u16* gA = A + (size_t)(m0 + r0g) * 1024 + kc;
  const u16* gB = Bt + (size_t)(n0 + r0g) * 1024 + kc;

#define QSTGA(D, H, C) \
  gload_lds16(gA + (size_t)(H) * 131072 + (C) * 65536, &sm[(D)][(H) * 8192 + (C) * 4096 + w * 512])
#define QSTGB(D, H, C) \
  gload_lds16(gB + (size_t)(H) * 131072 + (C) * 65536, &sm[(D)][16384 + (H) * 8192 + (C) * 4096 + w * 512])

  f32x4 acc[8][4];
#pragma unroll
  for (int i = 0; i < 8; ++i)
#pragma unroll
    for (int j = 0; j < 4; ++j) acc[i][j] = (f32x4){0, 0, 0, 0};

  // prologue: stage tile 0 -> buf 0, drain, barrier
  QSTGA(0, 0, 0); QSTGA(0, 0, 1); QSTGA(0, 1, 0); QSTGA(0, 1, 1);
  QSTGB(0, 0, 0); QSTGB(0, 0, 1); QSTGB(0, 1, 0); QSTGB(0, 1, 1);
  gA += 64; gB += 64;
  VMW0(); BAR();

#define QLDA(B_, KK, M0_)                                                 \
  _Pragma("unroll") for (int i = 0; i < 4; ++i)                           \
      av[i] = *(const bf16x8*)&sm[(B_)][aoff + (((M0_) + i) * 2 + (KK)) * 512];
#define QLDB(B_, KK)                                                      \
  _Pragma("unroll") for (int i = 0; i < 4; ++i)                           \
      bv[i] = *(const bf16x8*)&sm[(B_)][boff + (i * 2 + (KK)) * 512];
#define QMM(MB0)                                                          \
  __builtin_amdgcn_s_setprio(1);                                          \
  _Pragma("unroll") for (int i = 0; i < 4; ++i)                           \
      _Pragma("unroll") for (int j = 0; j < 4; ++j)                       \
          acc[(MB0) + i][j] = MFMA16(av[i], bv[j], acc[(MB0) + i][j]);    \
  __builtin_amdgcn_s_setprio(0);

#define QTILE(B_, S_)                                                          \
  {                                                                            \
    bf16x8 av[4], bv[4];                                                       \
    /* P1: A kk0 mb0-3 + B kk0; stage A(t+1) all 4 slices */                   \
    QLDA(B_, 0, 0) QLDB(B_, 0)                                                 \
    if (S_) { QSTGA((B_) ^ 1, 0, 0); QSTGA((B_) ^ 1, 0, 1);                    \
              QSTGA((B_) ^ 1, 1, 0); QSTGA((B_) ^ 1, 1, 1); }                  \
    BAR(); WLG(); QMM(0) BAR();                                                \
    /* P2: A kk0 mb4-7; stage B(t+1) all 4 slices */                           \
    QLDA(B_, 0, 4)                                                             \
    if (S_) { QSTGB((B_) ^ 1, 0, 0); QSTGB((B_) ^ 1, 0, 1);                    \
              QSTGB((B_) ^ 1, 1, 0); QSTGB((B_) ^ 1, 1, 1); }                  \
    BAR(); WLG(); QMM(4) BAR();                                                \
    /* P3: A kk1 mb0-3 + B kk1 */                                              \
    QLDA(B_, 1, 0) QLDB(B_, 1)                                                 \
    BAR(); WLG(); QMM(0) BAR();                                                \
    /* P4: A kk1 mb4-7; boundary drain (>=2 phases slack) */                   \
    QLDA(B_, 1, 4)                                                             \
    BAR(); WLG(); QMM(4)                                                       \
    if (S_) { VMW0(); gA += 64; gB += 64; }                                    \
    BAR();                                                                     \
  }

#pragma unroll 1
  for (int tp = 0; tp < 7; ++tp) { QTILE(0, 1) QTILE(1, 1) }
  QTILE(0, 1)  // t=14 (stages tile 15)
  QTILE(1, 0)  // t=15

  // epilogue: identical scatter semantics, 8 mb blocks
  const int which = n0 >> 10;  // block-uniform: 0=Q, 1=K, 2=V
#pragma unroll
  for (int nb = 0; nb < 4; ++nb) {
    const int n = n0 + wn * 64 + nb * 16 + fr;
    const float bs = bias[n];
    const int c = n & 1023, h = c >> 6, hd = c & 63;
#pragma unroll
    for (int mb = 0; mb < 8; ++mb) {
      const int mbase = m0 + wm * 128 + mb * 16 + fg * 4;
      const int bb = mbase >> 11;
      const int tt = mbase & 2047;
      if (which == 0) {
        u16* dst = Qo + ((size_t)(bb * 16 + h) * 2048 + tt) * 64 + hd;
#pragma unroll
        for (int r = 0; r < 4; ++r) dst[(size_t)r * 64] = f2bf((acc[mb][nb][r] + bs) * 0.125f);
      } else if (which == 1) {
        u16* dst = Ko + ((size_t)(bb * 16 + h) * 2048 + tt) * 64 + hd;
#pragma unroll
        for (int r = 0; r < 4; ++r) dst[(size_t)r * 64] = f2bf(acc[mb][nb][r] + bs);
      } else {
        ushort4 pv;
        pv.x = f2bf(acc[mb][nb][0] + bs);
        pv.y = f2bf(acc[mb][nb][1] + bs);
        pv.z = f2bf(acc[mb][nb][2] + bs);
        pv.w = f2bf(acc[mb][nb][3] + bs);
        *(ushort4*)(Vt + ((size_t)(bb * 16 + h) * 64 + hd) * 2048 + tt) = pv;
      }
    }
  }
#undef QSTGA
#undef QSTGB
#undef QLDA
#undef QLDB
#undef QMM
#undef QTILE
}

// ---------------- Proj GEMM: 256x128 tile, 8-phase; grid = 256 = 1 full round ----------------
__global__ __launch_bounds__(512, 2) void gemm_proj_8p(const u16* __restrict__ A,
                                                       const u16* __restrict__ Bt,
                                                       const float* __restrict__ bias,
                                                       float* __restrict__ O) {
  __shared__ u16 sm[2][24576];  // per buf: A [0,16384) u16, B [16384,24576)
  const int bid = blockIdx.x;
  const int swz = (bid & 7) * 32 + (bid >> 3);  // 256 % 8 == 0 -> bijective
  const int m0 = (swz >> 3) * 256, n0 = (swz & 7) * 128;
  LANE_CONSTS
  const int aoff = wm * 8192 + lsw;
  const int boff = 16384 + wn * 2048 + lsw;  // per-wave 32 B-rows

  const u16* gA = A + (size_t)(m0 + r0g) * 1024 + kc;
  const u16* gB = Bt + (size_t)(n0 + r0g) * 1024 + kc;

#define PSTGA(D, H, C) \
  gload_lds16(gA + (size_t)(H) * 131072 + (C) * 65536, &sm[(D)][(H) * 8192 + (C) * 4096 + w * 512])
#define PSTGB(D, C) \
  gload_lds16(gB + (size_t)(C) * 65536, &sm[(D)][16384 + (C) * 4096 + w * 512])

  f32x4 acc[8][2];
#pragma unroll
  for (int i = 0; i < 8; ++i)
#pragma unroll
    for (int j = 0; j < 2; ++j) acc[i][j] = (f32x4){0, 0, 0, 0};

  PSTGA(0, 0, 0); PSTGA(0, 0, 1); PSTGA(0, 1, 0); PSTGA(0, 1, 1);
  PSTGB(0, 0); PSTGB(0, 1);
  gA += 64; gB += 64;
  VMW0(); BAR();

#define PLDA(B_, KK, M0_)                                                 \
  _Pragma("unroll") for (int i = 0; i < 4; ++i)                           \
      av[i] = *(const bf16x8*)&sm[(B_)][aoff + (((M0_) + i) * 2 + (KK)) * 512];
#define PLDB(B_, KK)                                                      \
  _Pragma("unroll") for (int i = 0; i < 2; ++i)                           \
      bv[i] = *(const bf16x8*)&sm[(B_)][boff + (i * 2 + (KK)) * 512];
#define PMM(MB0)                                                          \
  __builtin_amdgcn_s_setprio(1);                                          \
  _Pragma("unroll") for (int i = 0; i < 4; ++i)                           \
      _Pragma("unroll") for (int j = 0; j < 2; ++j)                       \
          acc[(MB0) + i][j] = MFMA16(av[i], bv[j], acc[(MB0) + i][j]);    \
  __builtin_amdgcn_s_setprio(0);

#define PTILE(B_, S_)                                                          \
  {                                                                            \
    bf16x8 av[4], bv[2];                                                       \
    PLDA(B_, 0, 0) PLDB(B_, 0)                                                 \
    if (S_) { PSTGA((B_) ^ 1, 0, 0); PSTGA((B_) ^ 1, 0, 1);                    \
              PSTGA((B_) ^ 1, 1, 0); PSTGA((B_) ^ 1, 1, 1); }                  \
    BAR(); WLG(); PMM(0) BAR();                                                \
    PLDA(B_, 0, 4)                                                             \
    if (S_) { PSTGB((B_) ^ 1, 0); PSTGB((B_) ^ 1, 1); }                        \
    BAR(); WLG(); PMM(4) BAR();                                                \
    PLDA(B_, 1, 0) PLDB(B_, 1)                                                 \
    BAR(); WLG(); PMM(0) BAR();                                                \
    PLDA(B_, 1, 4)                                                             \
    BAR(); WLG(); PMM(4)                                                       \
    if (S_) { VMW0(); gA += 64; gB += 64; }                                    \
    BAR();                                                                     \
  }

#pragma unroll 1
  for (int tp = 0; tp < 7; ++tp) { PTILE(0, 1) PTILE(1, 1) }
  PTILE(0, 1)  // t=14 (stages tile 15)
  PTILE(1, 0)  // t=15

  // epilogue: classic C/D layout (col = fr -> n, row = fg*4+r -> m)
#pragma unroll
  for (int nb = 0; nb < 2; ++nb) {
    const int n = n0 + wn * 32 + nb * 16 + fr;
    const float bs = bias[n];
#pragma unroll
    for (int mb = 0; mb < 8; ++mb) {
      const int tg = m0 + wm * 128 + mb * 16 + fg * 4;
#pragma unroll
      for (int r = 0; r < 4; ++r) O[(size_t)(tg + r) * 1024 + n] = acc[mb][nb][r] + bs;
    }
  }
#undef PSTGA
#undef PSTGB
#undef PLDA
#undef PLDB
#undef PMM
#undef PTILE
}

// ---------------- Flash attention (R4/v4 form, measured best): 128 q/block (32/wave) ----------------
// S^T = K·Q^T (no max pass), O^T = V^T·P^T. PSTR=72 -> 36.9 KB LDS -> 4 blocks/CU.
#define PSTR 72
__global__ __launch_bounds__(256) void attn_k(const u16* __restrict__ Q,
                                              const u16* __restrict__ Kb,
                                              const u16* __restrict__ Vt,
                                              u16* __restrict__ Y) {
  __shared__ u16 Ks[64 * 72];
  __shared__ u16 Vs[64 * 72];
  __shared__ u16 Ps[4 * 32 * PSTR];
  const int L = blockIdx.x;
  const int xcd = L & 7, slot = L >> 3;
  const int bh = xcd * 8 + (slot & 7);
  const int qt = 15 - (slot >> 3);
  const int tid = threadIdx.x, w = tid >> 6, lane = tid & 63;
  const int fr = lane & 15, fg = lane >> 4;
  const u16* Qp = Q + (size_t)bh * 2048 * 64;
  const u16* Kp = Kb + (size_t)bh * 2048 * 64;
  const u16* Vp = Vt + (size_t)bh * 64 * 2048;
  const int qw = qt * 128 + w * 32;

  bf16x8 qa[2][2];
#pragma unroll
  for (int g = 0; g < 2; ++g)
#pragma unroll
    for (int c = 0; c < 2; ++c)
      qa[g][c] = *(const bf16x8*)(Qp + (size_t)(qw + g * 16 + fr) * 64 + c * 32 + fg * 8);

  float li[2] = {0.f, 0.f};
  f32x4 ot[2][4];
#pragma unroll
  for (int g = 0; g < 2; ++g)
#pragma unroll
    for (int mb = 0; mb < 4; ++mb) ot[g][mb] = (f32x4){0, 0, 0, 0};

  const int srow = tid >> 2, scol = (tid & 3) * 16;
  u16* Pw = Ps + w * 32 * PSTR;
  const int nk = 2 * qt + 2;
  const u16* Kg = Kp + (size_t)srow * 64 + scol;
  const u16* Vg = Vp + (size_t)srow * 2048 + scol;

  uint4 kr0 = *(const uint4*)(Kg);
  uint4 kr1 = *(const uint4*)(Kg + 8);
  uint4 vr0 = *(const uint4*)(Vg);
  uint4 vr1 = *(const uint4*)(Vg + 8);

  for (int jt = 0; jt < nk; ++jt) {
    const int k0 = jt * 64;
    if (jt) __syncthreads();
    *(uint4*)&Ks[srow * 72 + scol] = kr0;
    *(uint4*)&Ks[srow * 72 + scol + 8] = kr1;
    *(uint4*)&Vs[srow * 72 + scol] = vr0;
    *(uint4*)&Vs[srow * 72 + scol + 8] = vr1;
    __syncthreads();
    if (jt + 1 < nk) {
      const int kn = (jt + 1) * 64;
      kr0 = *(const uint4*)(Kg + (size_t)kn * 64);
      kr1 = *(const uint4*)(Kg + (size_t)kn * 64 + 8);
      vr0 = *(const uint4*)(Vg + kn);
      vr1 = *(const uint4*)(Vg + kn + 8);
    }
    if (k0 > qw + 31) continue;

    bf16x8 kb[4][2];
#pragma unroll
    for (int nb = 0; nb < 4; ++nb) {
      kb[nb][0] = *(const bf16x8*)&Ks[(nb * 16 + fr) * 72 + fg * 8];
      kb[nb][1] = *(const bf16x8*)&Ks[(nb * 16 + fr) * 72 + 32 + fg * 8];
    }
    f32x4 st[2][4];
#pragma unroll
    for (int g = 0; g < 2; ++g)
#pragma unroll
      for (int nb = 0; nb < 4; ++nb) {
        f32x4 z = (f32x4){0, 0, 0, 0};
        z = MFMA16(kb[nb][0], qa[g][0], z);
        z = MFMA16(kb[nb][1], qa[g][1], z);
        st[g][nb] = z;
      }
    const bool needmask = (k0 + 63 > qw);
#pragma unroll
    for (int g = 0; g < 2; ++g) {
      const int q = qw + g * 16 + fr;
      float rs0 = 0.f, rs1 = 0.f;
#pragma unroll
      for (int nb = 0; nb < 4; ++nb) {
        const int kcb = k0 + nb * 16 + 4 * fg;
        float p0 = __expf(st[g][nb][0]);
        float p1 = __expf(st[g][nb][1]);
        float p2 = __expf(st[g][nb][2]);
        float p3 = __expf(st[g][nb][3]);
        if (needmask) {
          p0 = (kcb + 0 > q) ? 0.f : p0;
          p1 = (kcb + 1 > q) ? 0.f : p1;
          p2 = (kcb + 2 > q) ? 0.f : p2;
          p3 = (kcb + 3 > q) ? 0.f : p3;
        }
        rs0 += p0 + p1;
        rs1 += p2 + p3;
        *(uint2*)&Pw[(g * 16 + fr) * PSTR + nb * 16 + 4 * fg] =
            make_uint2(pk_trunc(p1, p0), pk_trunc(p3, p2));
      }
      li[g] += rs0 + rs1;
    }
    bf16x8 pa[2][2];
#pragma unroll
    for (int g = 0; g < 2; ++g)
#pragma unroll
      for (int H = 0; H < 2; ++H)
        pa[g][H] = *(const bf16x8*)&Pw[(g * 16 + fr) * PSTR + H * 32 + fg * 8];
#pragma unroll
    for (int mb = 0; mb < 4; ++mb) {
      bf16x8 vb0 = *(const bf16x8*)&Vs[(mb * 16 + fr) * 72 + fg * 8];
      bf16x8 vb1 = *(const bf16x8*)&Vs[(mb * 16 + fr) * 72 + 32 + fg * 8];
#pragma unroll
      for (int g = 0; g < 2; ++g) {
        ot[g][mb] = MFMA16(vb0, pa[g][0], ot[g][mb]);
        ot[g][mb] = MFMA16(vb1, pa[g][1], ot[g][mb]);
      }
    }
  }

  const int b = bh >> 4, h = bh & 15;
#pragma unroll
  for (int g = 0; g < 2; ++g) {
    float l = li[g];
    l += __shfl_xor(l, 16);
    l += __shfl_xor(l, 32);
    const float inv = 1.0f / l;
    const int t = qw + g * 16 + fr;
    u16* yrow = Y + ((size_t)b * 2048 + t) * 1024 + h * 64;
#pragma unroll
    for (int mb = 0; mb < 4; ++mb) {
      const unsigned d0 = (unsigned)f2bf(ot[g][mb][0] * inv) |
                          ((unsigned)f2bf(ot[g][mb][1] * inv) << 16);
      const unsigned d1 = (unsigned)f2bf(ot[g][mb][2] * inv) |
                          ((unsigned)f2bf(ot[g][mb][3] * inv) << 16);
      *(uint2*)&yrow[mb * 16 + fg * 4] = make_uint2(d0, d1);
    }
  }
}

extern "C" void kernel_launch(void* const* d_in, const int* in_sizes, int n_in,
                              void* d_out, int out_size, void* d_ws, size_t ws_size,
                              hipStream_t stream) {
  const float* x = (const float*)d_in[0];
  const float* Wa = (const float*)d_in[1];
  const float* ba = (const float*)d_in[2];
  const float* Wp = (const float*)d_in[3];
  const float* bp = (const float*)d_in[4];
  float* out = (float*)d_out;

  char* p = (char*)d_ws;
  u16* xb = (u16*)p;   p += (size_t)8192 * 1024 * 2;
  u16* WaT = (u16*)p;  p += (size_t)3072 * 1024 * 2;
  u16* WpT = (u16*)p;  p += (size_t)1024 * 1024 * 2;
  u16* Qb = (u16*)p;   p += (size_t)64 * 2048 * 64 * 2;
  u16* Kbuf = (u16*)p; p += (size_t)64 * 2048 * 64 * 2;
  u16* Vtb = (u16*)p;  p += (size_t)64 * 64 * 2048 * 2;
  u16* Yb = (u16*)p;   p += (size_t)8192 * 1024 * 2;

  convert_bf16_k<<<4096, 256, 0, stream>>>(x, xb, 8192 * 1024);
  transpose2_k<<<1024, 256, 0, stream>>>(Wa, WaT, Wp, WpT);
  gemm_qkv_8p<<<384, 512, 0, stream>>>(xb, WaT, ba, Qb, Kbuf, Vtb);
  attn_k<<<1024, 256, 0, stream>>>(Qb, Kbuf, Vtb, Yb);
  gemm_proj_8p<<<256, 512, 0, stream>>>(Yb, WpT, bp, out);
}

// Round 3
// 250.802 us; speedup vs baseline: 1.0739x; 1.0140x over previous
//
#include <hip/hip_runtime.h>
#include <hip/hip_bf16.h>

typedef unsigned short u16;
typedef __attribute__((ext_vector_type(8))) short bf16x8;
typedef __attribute__((ext_vector_type(4))) float f32x4;

#define MFMA16(a, b, c) __builtin_amdgcn_mfma_f32_16x16x32_bf16((a), (b), (c), 0, 0, 0)

__device__ __forceinline__ u16 f2bf(float f) {
  union { float f; unsigned u; } v; v.f = f;
  unsigned r = v.u + 0x7fffu + ((v.u >> 16) & 1u);  // RNE
  return (u16)(r >> 16);
}

// pack two fp32 -> dword of 2 bf16 by truncation (1 VALU op)
__device__ __forceinline__ unsigned pk_trunc(float hi, float lo) {
  union { float f; unsigned u; } a, b; a.f = hi; b.f = lo;
  return __builtin_amdgcn_perm(a.u, b.u, 0x07060302u);
}

__device__ __forceinline__ void gload_lds16(const u16* g, u16* l) {
  __builtin_amdgcn_global_load_lds((const __attribute__((address_space(1))) void*)g,
                                   (__attribute__((address_space(3))) void*)l, 16, 0, 0);
}

// ---------------- fp32 -> bf16 convert: 8 elems/thread ----------------
__global__ __launch_bounds__(256) void convert_bf16_k(const float* __restrict__ in,
                                                      u16* __restrict__ out, int n) {
  int i = (blockIdx.x * 256 + threadIdx.x) * 8;
  if (i >= n) return;
  float4 v0 = *(const float4*)(in + i);
  float4 v1 = *(const float4*)(in + i + 4);
  uint4 o;
  o.x = (unsigned)f2bf(v0.x) | ((unsigned)f2bf(v0.y) << 16);
  o.y = (unsigned)f2bf(v0.z) | ((unsigned)f2bf(v0.w) << 16);
  o.z = (unsigned)f2bf(v1.x) | ((unsigned)f2bf(v1.y) << 16);
  o.w = (unsigned)f2bf(v1.z) | ((unsigned)f2bf(v1.w) << 16);
  *(uint4*)(out + i) = o;
}

// ---------------- fused transposes: Wa [1024][3072] and Wp [1024][1024] -> bf16 [N][K] ----------------
__global__ __launch_bounds__(256) void transpose2_k(const float* __restrict__ Wa, u16* __restrict__ WaT,
                                                    const float* __restrict__ Wp, u16* __restrict__ WpT) {
  __shared__ float tile[64][65];
  int b = blockIdx.x;
  const float* W; u16* Wt; int N, n0, k0;
  if (b < 768) { W = Wa; Wt = WaT; N = 3072; n0 = (b % 48) * 64; k0 = (b / 48) * 64; }
  else { int c = b - 768; W = Wp; Wt = WpT; N = 1024; n0 = (c & 15) * 64; k0 = (c >> 4) * 64; }
  const int tx = threadIdx.x & 63, ty = threadIdx.x >> 6;
#pragma unroll
  for (int i = 0; i < 16; ++i)
    tile[ty + 4 * i][tx] = W[(size_t)(k0 + ty + 4 * i) * N + n0 + tx];
  __syncthreads();
#pragma unroll
  for (int i = 0; i < 16; ++i)
    Wt[(size_t)(n0 + ty + 4 * i) * 1024 + k0 + tx] = f2bf(tile[tx][ty + 4 * i]);
}

// ---------------- 8-phase 256-wide GEMM core (T1+T2+T3+T4+T5) ----------------
// 512 thr / 8 waves (2M x 4N). st_16x32 swizzle: linear gload_lds dest +
// inverse-swizzled global src + swizzled ds_read (rule 21).
// T4: counted vmcnt(2) at P1/P4 — NEVER vmcnt(0) in the main loop (m218).
// Stage plan per tile t (for t+1): P1 A-C0, P2 B-H0, P3 B-H1 + A-C1, P4 none.
#define BAR() asm volatile("s_barrier" ::: "memory")
#define WLG()                                                   \
  do {                                                          \
    asm volatile("s_waitcnt lgkmcnt(0)" ::: "memory");          \
    __builtin_amdgcn_sched_barrier(0);                          \
  } while (0)
#define VMW(N) asm volatile("s_waitcnt vmcnt(" #N ")" ::: "memory")

#define LANE_CONSTS                                                       \
  const int tid = threadIdx.x, w = tid >> 6, lane = tid & 63;             \
  const int wm = w >> 2, wn = w & 3;                                      \
  const int fr = lane & 15, fg = lane >> 4;                               \
  const int sr = lane >> 2;                                               \
  const int sk = (lane & 1) * 8 + ((((lane >> 1) ^ (lane >> 5)) & 1) << 4); \
  const int kc = (w & 1) * 32 + sk;                                       \
  const int r0g = (w >> 1) * 16 + sr;                                     \
  const int lsw = fr * 32 + ((fg * 8) ^ ((fr & 8) ? 16 : 0));

// ---------------- QKV GEMM: 256x256 tile, K=1024 (16 K-tiles of 64) ----------------
__global__ __launch_bounds__(512, 2) void gemm_qkv_8p(const u16* __restrict__ A,
                                                      const u16* __restrict__ Bt,
                                                      const float* __restrict__ bias,
                                                      u16* __restrict__ Qo, u16* __restrict__ Ko,
                                                      u16* __restrict__ Vt) {
  __shared__ u16 sm[2][32768];  // per buf: A [0,16384) u16, B [16384,32768)
  const int bid = blockIdx.x;
  const int swz = (bid & 7) * 48 + (bid >> 3);  // 384 % 8 == 0 -> bijective
  const int m0 = (swz / 12) * 256, n0 = (swz % 12) * 256;
  LANE_CONSTS
  const int aoff = wm * 8192 + lsw;
  const int boff = 16384 + (wn >> 1) * 8192 + (wn & 1) * 4096 + lsw;

  const u16* gA = A + (size_t)(m0 + r0g) * 1024 + kc;
  const u16* gB = Bt + (size_t)(n0 + r0g) * 1024 + kc;

#define QSTGA(D, H, C) \
  gload_lds16(gA + (size_t)(H) * 131072 + (C) * 65536, &sm[(D)][(H) * 8192 + (C) * 4096 + w * 512])
#define QSTGB(D, H, C) \
  gload_lds16(gB + (size_t)(H) * 131072 + (C) * 65536, &sm[(D)][16384 + (H) * 8192 + (C) * 4096 + w * 512])

  f32x4 acc[8][4];
#pragma unroll
  for (int i = 0; i < 8; ++i)
#pragma unroll
    for (int j = 0; j < 4; ++j) acc[i][j] = (f32x4){0, 0, 0, 0};

  // prologue: stage tile 0 -> buf 0, drain, barrier
  QSTGA(0, 0, 0); QSTGA(0, 0, 1); QSTGA(0, 1, 0); QSTGA(0, 1, 1);
  QSTGB(0, 0, 0); QSTGB(0, 0, 1); QSTGB(0, 1, 0); QSTGB(0, 1, 1);
  gA += 64; gB += 64;
  VMW(0); BAR();

#define QLDA(B_, KK, M0_)                                                 \
  _Pragma("unroll") for (int i = 0; i < 4; ++i)                           \
      av[i] = *(const bf16x8*)&sm[(B_)][aoff + (((M0_) + i) * 2 + (KK)) * 512];
#define QLDB(B_, KK)                                                      \
  _Pragma("unroll") for (int i = 0; i < 4; ++i)                           \
      bv[i] = *(const bf16x8*)&sm[(B_)][boff + (i * 2 + (KK)) * 512];
#define QMM(MB0)                                                          \
  __builtin_amdgcn_s_setprio(1);                                          \
  _Pragma("unroll") for (int i = 0; i < 4; ++i)                           \
      _Pragma("unroll") for (int j = 0; j < 4; ++j)                       \
          acc[(MB0) + i][j] = MFMA16(av[i], bv[j], acc[(MB0) + i][j]);    \
  __builtin_amdgcn_s_setprio(0);

// Per-wave VMEM issue order (steady state, 8 stage calls/tile for t+1):
//   [tP1: A-C0 x2][tP2: B-H0 x2][tP3: B-H1 x2 + A-C1 x2] -> 8 in flight at P4 end.
// end-P1 vmcnt(2): retires A-C1(t) (issued t-1 P3) before P2's ds_reads.
// end-P4 vmcnt(2): retires A-C0(t+1)+B(t+1) (first 6) before t+1 P1's ds_reads;
//                  A-C1(t+1) stays in flight across the boundary (never drain to 0).
#define QTILE(B_, S_)                                                          \
  {                                                                            \
    bf16x8 av[4], bv[4];                                                       \
    /* P1: read A-C0 kk0 + B kk0; stage A-C0(t+1) */                           \
    QLDA(B_, 0, 0) QLDB(B_, 0)                                                 \
    if (S_) { QSTGA((B_) ^ 1, 0, 0); QSTGA((B_) ^ 1, 1, 0); }                  \
    BAR(); WLG(); QMM(0)                                                       \
    if (S_) { VMW(2); } else { VMW(0); }                                       \
    BAR();                                                                     \
    /* P2: read A-C1 kk0; stage B-H0(t+1) */                                   \
    QLDA(B_, 0, 4)                                                             \
    if (S_) { QSTGB((B_) ^ 1, 0, 0); QSTGB((B_) ^ 1, 0, 1); }                  \
    BAR(); WLG(); QMM(4) BAR();                                                \
    /* P3: read A-C0 kk1 + B kk1; stage B-H1(t+1) + A-C1(t+1) */               \
    QLDA(B_, 1, 0) QLDB(B_, 1)                                                 \
    if (S_) { QSTGB((B_) ^ 1, 1, 0); QSTGB((B_) ^ 1, 1, 1);                    \
              QSTGA((B_) ^ 1, 0, 1); QSTGA((B_) ^ 1, 1, 1); }                  \
    BAR(); WLG(); QMM(0) BAR();                                                \
    /* P4: read A-C1 kk1; counted boundary checkpoint */                       \
    QLDA(B_, 1, 4)                                                             \
    BAR(); WLG(); QMM(4)                                                       \
    if (S_) { VMW(2); gA += 64; gB += 64; }                                    \
    BAR();                                                                     \
  }

#pragma unroll 1
  for (int tp = 0; tp < 7; ++tp) { QTILE(0, 1) QTILE(1, 1) }
  QTILE(0, 1)  // t=14 (stages tile 15)
  QTILE(1, 0)  // t=15

  // epilogue: identical scatter semantics, 8 mb blocks
  const int which = n0 >> 10;  // block-uniform: 0=Q, 1=K, 2=V
#pragma unroll
  for (int nb = 0; nb < 4; ++nb) {
    const int n = n0 + wn * 64 + nb * 16 + fr;
    const float bs = bias[n];
    const int c = n & 1023, h = c >> 6, hd = c & 63;
#pragma unroll
    for (int mb = 0; mb < 8; ++mb) {
      const int mbase = m0 + wm * 128 + mb * 16 + fg * 4;
      const int bb = mbase >> 11;
      const int tt = mbase & 2047;
      if (which == 0) {
        u16* dst = Qo + ((size_t)(bb * 16 + h) * 2048 + tt) * 64 + hd;
#pragma unroll
        for (int r = 0; r < 4; ++r) dst[(size_t)r * 64] = f2bf((acc[mb][nb][r] + bs) * 0.125f);
      } else if (which == 1) {
        u16* dst = Ko + ((size_t)(bb * 16 + h) * 2048 + tt) * 64 + hd;
#pragma unroll
        for (int r = 0; r < 4; ++r) dst[(size_t)r * 64] = f2bf(acc[mb][nb][r] + bs);
      } else {
        ushort4 pv;
        pv.x = f2bf(acc[mb][nb][0] + bs);
        pv.y = f2bf(acc[mb][nb][1] + bs);
        pv.z = f2bf(acc[mb][nb][2] + bs);
        pv.w = f2bf(acc[mb][nb][3] + bs);
        *(ushort4*)(Vt + ((size_t)(bb * 16 + h) * 64 + hd) * 2048 + tt) = pv;
      }
    }
  }
#undef QSTGA
#undef QSTGB
#undef QLDA
#undef QLDB
#undef QMM
#undef QTILE
}

// ---------------- Proj GEMM: 256x128 tile, 8-phase counted; grid = 256 = 1 full round ----------------
__global__ __launch_bounds__(512, 2) void gemm_proj_8p(const u16* __restrict__ A,
                                                       const u16* __restrict__ Bt,
                                                       const float* __restrict__ bias,
                                                       float* __restrict__ O) {
  __shared__ u16 sm[2][24576];  // per buf: A [0,16384) u16, B [16384,24576)
  const int bid = blockIdx.x;
  const int swz = (bid & 7) * 32 + (bid >> 3);  // 256 % 8 == 0 -> bijective
  const int m0 = (swz >> 3) * 256, n0 = (swz & 7) * 128;
  LANE_CONSTS
  const int aoff = wm * 8192 + lsw;
  const int boff = 16384 + wn * 2048 + lsw;  // per-wave 32 B-rows

  const u16* gA = A + (size_t)(m0 + r0g) * 1024 + kc;
  const u16* gB = Bt + (size_t)(n0 + r0g) * 1024 + kc;

#define PSTGA(D, H, C) \
  gload_lds16(gA + (size_t)(H) * 131072 + (C) * 65536, &sm[(D)][(H) * 8192 + (C) * 4096 + w * 512])
#define PSTGB(D, C) \
  gload_lds16(gB + (size_t)(C) * 65536, &sm[(D)][16384 + (C) * 4096 + w * 512])

  f32x4 acc[8][2];
#pragma unroll
  for (int i = 0; i < 8; ++i)
#pragma unroll
    for (int j = 0; j < 2; ++j) acc[i][j] = (f32x4){0, 0, 0, 0};

  PSTGA(0, 0, 0); PSTGA(0, 0, 1); PSTGA(0, 1, 0); PSTGA(0, 1, 1);
  PSTGB(0, 0); PSTGB(0, 1);
  gA += 64; gB += 64;
  VMW(0); BAR();

#define PLDA(B_, KK, M0_)                                                 \
  _Pragma("unroll") for (int i = 0; i < 4; ++i)                           \
      av[i] = *(const bf16x8*)&sm[(B_)][aoff + (((M0_) + i) * 2 + (KK)) * 512];
#define PLDB(B_, KK)                                                      \
  _Pragma("unroll") for (int i = 0; i < 2; ++i)                           \
      bv[i] = *(const bf16x8*)&sm[(B_)][boff + (i * 2 + (KK)) * 512];
#define PMM(MB0)                                                          \
  __builtin_amdgcn_s_setprio(1);                                          \
  _Pragma("unroll") for (int i = 0; i < 4; ++i)                           \
      _Pragma("unroll") for (int j = 0; j < 2; ++j)                       \
          acc[(MB0) + i][j] = MFMA16(av[i], bv[j], acc[(MB0) + i][j]);    \
  __builtin_amdgcn_s_setprio(0);

// Issue order: [tP1: A-C0 x2][tP2: B x2][tP3: A-C1 x2] -> 6 in flight at P4 end.
// end-P1 vmcnt(2): retires A-C1(t). end-P4 vmcnt(2): retires A-C0(t+1)+B(t+1).
#define PTILE(B_, S_)                                                          \
  {                                                                            \
    bf16x8 av[4], bv[2];                                                       \
    PLDA(B_, 0, 0) PLDB(B_, 0)                                                 \
    if (S_) { PSTGA((B_) ^ 1, 0, 0); PSTGA((B_) ^ 1, 1, 0); }                  \
    BAR(); WLG(); PMM(0)                                                       \
    if (S_) { VMW(2); } else { VMW(0); }                                       \
    BAR();                                                                     \
    PLDA(B_, 0, 4)                                                             \
    if (S_) { PSTGB((B_) ^ 1, 0); PSTGB((B_) ^ 1, 1); }                        \
    BAR(); WLG(); PMM(4) BAR();                                                \
    PLDA(B_, 1, 0) PLDB(B_, 1)                                                 \
    if (S_) { PSTGA((B_) ^ 1, 0, 1); PSTGA((B_) ^ 1, 1, 1); }                  \
    BAR(); WLG(); PMM(0) BAR();                                                \
    PLDA(B_, 1, 4)                                                             \
    BAR(); WLG(); PMM(4)                                                       \
    if (S_) { VMW(2); gA += 64; gB += 64; }                                    \
    BAR();                                                                     \
  }

#pragma unroll 1
  for (int tp = 0; tp < 7; ++tp) { PTILE(0, 1) PTILE(1, 1) }
  PTILE(0, 1)  // t=14 (stages tile 15)
  PTILE(1, 0)  // t=15

  // epilogue: classic C/D layout (col = fr -> n, row = fg*4+r -> m)
#pragma unroll
  for (int nb = 0; nb < 2; ++nb) {
    const int n = n0 + wn * 32 + nb * 16 + fr;
    const float bs = bias[n];
#pragma unroll
    for (int mb = 0; mb < 8; ++mb) {
      const int tg = m0 + wm * 128 + mb * 16 + fg * 4;
#pragma unroll
      for (int r = 0; r < 4; ++r) O[(size_t)(tg + r) * 1024 + n] = acc[mb][nb][r] + bs;
    }
  }
#undef PSTGA
#undef PSTGB
#undef PLDA
#undef PLDB
#undef PMM
#undef PTILE
}

// ---------------- Flash attention (R4/v4 form, measured best): 128 q/block (32/wave) ----------------
// S^T = K·Q^T (no max pass), O^T = V^T·P^T. PSTR=72 -> 36.9 KB LDS -> 4 blocks/CU.
#define PSTR 72
__global__ __launch_bounds__(256) void attn_k(const u16* __restrict__ Q,
                                              const u16* __restrict__ Kb,
                                              const u16* __restrict__ Vt,
                                              u16* __restrict__ Y) {
  __shared__ u16 Ks[64 * 72];
  __shared__ u16 Vs[64 * 72];
  __shared__ u16 Ps[4 * 32 * PSTR];
  const int L = blockIdx.x;
  const int xcd = L & 7, slot = L >> 3;
  const int bh = xcd * 8 + (slot & 7);
  const int qt = 15 - (slot >> 3);
  const int tid = threadIdx.x, w = tid >> 6, lane = tid & 63;
  const int fr = lane & 15, fg = lane >> 4;
  const u16* Qp = Q + (size_t)bh * 2048 * 64;
  const u16* Kp = Kb + (size_t)bh * 2048 * 64;
  const u16* Vp = Vt + (size_t)bh * 64 * 2048;
  const int qw = qt * 128 + w * 32;

  bf16x8 qa[2][2];
#pragma unroll
  for (int g = 0; g < 2; ++g)
#pragma unroll
    for (int c = 0; c < 2; ++c)
      qa[g][c] = *(const bf16x8*)(Qp + (size_t)(qw + g * 16 + fr) * 64 + c * 32 + fg * 8);

  float li[2] = {0.f, 0.f};
  f32x4 ot[2][4];
#pragma unroll
  for (int g = 0; g < 2; ++g)
#pragma unroll
    for (int mb = 0; mb < 4; ++mb) ot[g][mb] = (f32x4){0, 0, 0, 0};

  const int srow = tid >> 2, scol = (tid & 3) * 16;
  u16* Pw = Ps + w * 32 * PSTR;
  const int nk = 2 * qt + 2;
  const u16* Kg = Kp + (size_t)srow * 64 + scol;
  const u16* Vg = Vp + (size_t)srow * 2048 + scol;

  uint4 kr0 = *(const uint4*)(Kg);
  uint4 kr1 = *(const uint4*)(Kg + 8);
  uint4 vr0 = *(const uint4*)(Vg);
  uint4 vr1 = *(const uint4*)(Vg + 8);

  for (int jt = 0; jt < nk; ++jt) {
    const int k0 = jt * 64;
    if (jt) __syncthreads();
    *(uint4*)&Ks[srow * 72 + scol] = kr0;
    *(uint4*)&Ks[srow * 72 + scol + 8] = kr1;
    *(uint4*)&Vs[srow * 72 + scol] = vr0;
    *(uint4*)&Vs[srow * 72 + scol + 8] = vr1;
    __syncthreads();
    if (jt + 1 < nk) {
      const int kn = (jt + 1) * 64;
      kr0 = *(const uint4*)(Kg + (size_t)kn * 64);
      kr1 = *(const uint4*)(Kg + (size_t)kn * 64 + 8);
      vr0 = *(const uint4*)(Vg + kn);
      vr1 = *(const uint4*)(Vg + kn + 8);
    }
    if (k0 > qw + 31) continue;

    bf16x8 kb[4][2];
#pragma unroll
    for (int nb = 0; nb < 4; ++nb) {
      kb[nb][0] = *(const bf16x8*)&Ks[(nb * 16 + fr) * 72 + fg * 8];
      kb[nb][1] = *(const bf16x8*)&Ks[(nb * 16 + fr) * 72 + 32 + fg * 8];
    }
    f32x4 st[2][4];
#pragma unroll
    for (int g = 0; g < 2; ++g)
#pragma unroll
      for (int nb = 0; nb < 4; ++nb) {
        f32x4 z = (f32x4){0, 0, 0, 0};
        z = MFMA16(kb[nb][0], qa[g][0], z);
        z = MFMA16(kb[nb][1], qa[g][1], z);
        st[g][nb] = z;
      }
    const bool needmask = (k0 + 63 > qw);
#pragma unroll
    for (int g = 0; g < 2; ++g) {
      const int q = qw + g * 16 + fr;
      float rs0 = 0.f, rs1 = 0.f;
#pragma unroll
      for (int nb = 0; nb < 4; ++nb) {
        const int kcb = k0 + nb * 16 + 4 * fg;
        float p0 = __expf(st[g][nb][0]);
        float p1 = __expf(st[g][nb][1]);
        float p2 = __expf(st[g][nb][2]);
        float p3 = __expf(st[g][nb][3]);
        if (needmask) {
          p0 = (kcb + 0 > q) ? 0.f : p0;
          p1 = (kcb + 1 > q) ? 0.f : p1;
          p2 = (kcb + 2 > q) ? 0.f : p2;
          p3 = (kcb + 3 > q) ? 0.f : p3;
        }
        rs0 += p0 + p1;
        rs1 += p2 + p3;
        *(uint2*)&Pw[(g * 16 + fr) * PSTR + nb * 16 + 4 * fg] =
            make_uint2(pk_trunc(p1, p0), pk_trunc(p3, p2));
      }
      li[g] += rs0 + rs1;
    }
    bf16x8 pa[2][2];
#pragma unroll
    for (int g = 0; g < 2; ++g)
#pragma unroll
      for (int H = 0; H < 2; ++H)
        pa[g][H] = *(const bf16x8*)&Pw[(g * 16 + fr) * PSTR + H * 32 + fg * 8];
#pragma unroll
    for (int mb = 0; mb < 4; ++mb) {
      bf16x8 vb0 = *(const bf16x8*)&Vs[(mb * 16 + fr) * 72 + fg * 8];
      bf16x8 vb1 = *(const bf16x8*)&Vs[(mb * 16 + fr) * 72 + 32 + fg * 8];
#pragma unroll
      for (int g = 0; g < 2; ++g) {
        ot[g][mb] = MFMA16(vb0, pa[g][0], ot[g][mb]);
        ot[g][mb] = MFMA16(vb1, pa[g][1], ot[g][mb]);
      }
    }
  }

  const int b = bh >> 4, h = bh & 15;
#pragma unroll
  for (int g = 0; g < 2; ++g) {
    float l = li[g];
    l += __shfl_xor(l, 16);
    l += __shfl_xor(l, 32);
    const float inv = 1.0f / l;
    const int t = qw + g * 16 + fr;
    u16* yrow = Y + ((size_t)b * 2048 + t) * 1024 + h * 64;
#pragma unroll
    for (int mb = 0; mb < 4; ++mb) {
      const unsigned d0 = (unsigned)f2bf(ot[g][mb][0] * inv) |
                          ((unsigned)f2bf(ot[g][mb][1] * inv) << 16);
      const unsigned d1 = (unsigned)f2bf(ot[g][mb][2] * inv) |
                          ((unsigned)f2bf(ot[g][mb][3] * inv) << 16);
      *(uint2*)&yrow[mb * 16 + fg * 4] = make_uint2(d0, d1);
    }
  }
}

extern "C" void kernel_launch(void* const* d_in, const int* in_sizes, int n_in,
                              void* d_out, int out_size, void* d_ws, size_t ws_size,
                              hipStream_t stream) {
  const float* x = (const float*)d_in[0];
  const float* Wa = (const float*)d_in[1];
  const float* ba = (const float*)d_in[2];
  const float* Wp = (const float*)d_in[3];
  const float* bp = (const float*)d_in[4];
  float* out = (float*)d_out;

  char* p = (char*)d_ws;
  u16* xb = (u16*)p;   p += (size_t)8192 * 1024 * 2;
  u16* WaT = (u16*)p;  p += (size_t)3072 * 1024 * 2;
  u16* WpT = (u16*)p;  p += (size_t)1024 * 1024 * 2;
  u16* Qb = (u16*)p;   p += (size_t)64 * 2048 * 64 * 2;
  u16* Kbuf = (u16*)p; p += (size_t)64 * 2048 * 64 * 2;
  u16* Vtb = (u16*)p;  p += (size_t)64 * 64 * 2048 * 2;
  u16* Yb = (u16*)p;   p += (size_t)8192 * 1024 * 2;

  convert_bf16_k<<<4096, 256, 0, stream>>>(x, xb, 8192 * 1024);
  transpose2_k<<<1024, 256, 0, stream>>>(Wa, WaT, Wp, WpT);
  gemm_qkv_8p<<<384, 512, 0, stream>>>(xb, WaT, ba, Qb, Kbuf, Vtb);
  attn_k<<<1024, 256, 0, stream>>>(Qb, Kbuf, Vtb, Yb);
  gemm_proj_8p<<<256, 512, 0, stream>>>(Yb, WpT, bp, out);
}

// Round 4
// 250.567 us; speedup vs baseline: 1.0749x; 1.0009x over previous
//
#include <hip/hip_runtime.h>
#include <hip/hip_bf16.h>

typedef unsigned short u16;
typedef __attribute__((ext_vector_type(8))) short bf16x8;
typedef __attribute__((ext_vector_type(4))) float f32x4;

#define MFMA16(a, b, c) __builtin_amdgcn_mfma_f32_16x16x32_bf16((a), (b), (c), 0, 0, 0)

__device__ __forceinline__ u16 f2bf(float f) {
  union { float f; unsigned u; } v; v.f = f;
  unsigned r = v.u + 0x7fffu + ((v.u >> 16) & 1u);  // RNE
  return (u16)(r >> 16);
}

// pack two fp32 -> dword of 2 bf16 by truncation (1 VALU op)
__device__ __forceinline__ unsigned pk_trunc(float hi, float lo) {
  union { float f; unsigned u; } a, b; a.f = hi; b.f = lo;
  return __builtin_amdgcn_perm(a.u, b.u, 0x07060302u);
}

__device__ __forceinline__ void gload_lds16(const u16* g, u16* l) {
  __builtin_amdgcn_global_load_lds((const __attribute__((address_space(1))) void*)g,
                                   (__attribute__((address_space(3))) void*)l, 16, 0, 0);
}

// ---------------- fp32 -> bf16 convert: 8 elems/thread ----------------
__global__ __launch_bounds__(256) void convert_bf16_k(const float* __restrict__ in,
                                                      u16* __restrict__ out, int n) {
  int i = (blockIdx.x * 256 + threadIdx.x) * 8;
  if (i >= n) return;
  float4 v0 = *(const float4*)(in + i);
  float4 v1 = *(const float4*)(in + i + 4);
  uint4 o;
  o.x = (unsigned)f2bf(v0.x) | ((unsigned)f2bf(v0.y) << 16);
  o.y = (unsigned)f2bf(v0.z) | ((unsigned)f2bf(v0.w) << 16);
  o.z = (unsigned)f2bf(v1.x) | ((unsigned)f2bf(v1.y) << 16);
  o.w = (unsigned)f2bf(v1.z) | ((unsigned)f2bf(v1.w) << 16);
  *(uint4*)(out + i) = o;
}

// ---------------- fused transposes: Wa [1024][3072] and Wp [1024][1024] -> bf16 [N][K] ----------------
__global__ __launch_bounds__(256) void transpose2_k(const float* __restrict__ Wa, u16* __restrict__ WaT,
                                                    const float* __restrict__ Wp, u16* __restrict__ WpT) {
  __shared__ float tile[64][65];
  int b = blockIdx.x;
  const float* W; u16* Wt; int N, n0, k0;
  if (b < 768) { W = Wa; Wt = WaT; N = 3072; n0 = (b % 48) * 64; k0 = (b / 48) * 64; }
  else { int c = b - 768; W = Wp; Wt = WpT; N = 1024; n0 = (c & 15) * 64; k0 = (c >> 4) * 64; }
  const int tx = threadIdx.x & 63, ty = threadIdx.x >> 6;
#pragma unroll
  for (int i = 0; i < 16; ++i)
    tile[ty + 4 * i][tx] = W[(size_t)(k0 + ty + 4 * i) * N + n0 + tx];
  __syncthreads();
#pragma unroll
  for (int i = 0; i < 16; ++i)
    Wt[(size_t)(n0 + ty + 4 * i) * 1024 + k0 + tx] = f2bf(tile[tx][ty + 4 * i]);
}

// ---------------- co-resident GEMM core: BK=32, 256 thr (4 waves 1M x 4N) ----------------
// Theory: reg budget ~200/wave -> 2 waves/SIMD -> 2+ blocks/CU with INDEPENDENT
// barriers (m114 overlap; m97's 912 TF mechanism). One __syncthreads per K-tile,
// stage-first so the implicit vmcnt(0) drain has ~800 cyc of compute cover.
// LDS swizzle for BK=32: col8 ^= ((row>>1)&3)<<3  (bank = 16(row&1)+4*grp -> 2-way max).

#define GEMM_LANE_CONSTS                                                    \
  const int tid = threadIdx.x, w = tid >> 6, lane = tid & 63;               \
  const int fr = lane & 15, fg = lane >> 4;                                 \
  const int swS = ((fr >> 1) & 3) << 3;                                     \
  const int srow = tid >> 2;                                                \
  const int scol = ((tid & 3) * 8) ^ (((tid >> 3) & 3) << 3);

// ---------------- QKV GEMM: 128x256 tile, K=1024 (32 K-tiles of 32) ----------------
__global__ __launch_bounds__(256, 2) void gemm_qkv_v2(const u16* __restrict__ A,
                                                      const u16* __restrict__ Bt,
                                                      const float* __restrict__ bias,
                                                      u16* __restrict__ Qo, u16* __restrict__ Ko,
                                                      u16* __restrict__ Vt) {
  __shared__ u16 sm[2][12288];  // per buf: A [0,4096) = [128][32], B [4096,12288) = [256][32]
  const int bid = blockIdx.x;
  const int swz = (bid & 7) * 96 + (bid >> 3);  // 768 % 8 == 0 -> bijective XCD swizzle
  const int m0 = (swz / 12) * 128, n0 = (swz % 12) * 256;
  GEMM_LANE_CONSTS

  const u16* gA = A + (size_t)(m0 + srow) * 1024 + scol;
  const u16* gB = Bt + (size_t)(n0 + srow) * 1024 + scol;

#define VSTGA(D, C) gload_lds16(gA + (size_t)(C) * 65536, &sm[(D)][(C) * 2048 + tid * 8])
#define VSTGB(D, C) gload_lds16(gB + (size_t)(C) * 65536, &sm[(D)][4096 + (C) * 2048 + tid * 8])

  f32x4 acc[8][4];
#pragma unroll
  for (int i = 0; i < 8; ++i)
#pragma unroll
    for (int j = 0; j < 4; ++j) acc[i][j] = (f32x4){0, 0, 0, 0};

  // prologue: stage tile 0 -> buf 0
  VSTGA(0, 0); VSTGA(0, 1);
  VSTGB(0, 0); VSTGB(0, 1); VSTGB(0, 2); VSTGB(0, 3);
  gA += 32; gB += 32;
  __syncthreads();

  const int aoff = fr * 32 + ((fg * 8) ^ swS);
  const int boff = 4096 + w * 2048 + fr * 32 + ((fg * 8) ^ swS);

#define VTILE(B_, S_)                                                          \
  {                                                                            \
    if (S_) { VSTGA((B_) ^ 1, 0); VSTGA((B_) ^ 1, 1);                          \
              VSTGB((B_) ^ 1, 0); VSTGB((B_) ^ 1, 1);                          \
              VSTGB((B_) ^ 1, 2); VSTGB((B_) ^ 1, 3); }                        \
    bf16x8 av[4], bv[4];                                                       \
    _Pragma("unroll") for (int nb = 0; nb < 4; ++nb)                           \
        bv[nb] = *(const bf16x8*)&sm[(B_)][boff + nb * 512];                   \
    _Pragma("unroll") for (int i = 0; i < 4; ++i)                              \
        av[i] = *(const bf16x8*)&sm[(B_)][aoff + i * 512];                     \
    _Pragma("unroll") for (int i = 0; i < 4; ++i)                              \
        _Pragma("unroll") for (int nb = 0; nb < 4; ++nb)                       \
            acc[i][nb] = MFMA16(av[i], bv[nb], acc[i][nb]);                    \
    _Pragma("unroll") for (int i = 0; i < 4; ++i)                              \
        av[i] = *(const bf16x8*)&sm[(B_)][aoff + (4 + i) * 512];               \
    _Pragma("unroll") for (int i = 0; i < 4; ++i)                              \
        _Pragma("unroll") for (int nb = 0; nb < 4; ++nb)                       \
            acc[4 + i][nb] = MFMA16(av[i], bv[nb], acc[4 + i][nb]);            \
    if (S_) { gA += 32; gB += 32; }                                            \
    __syncthreads();                                                           \
  }

#pragma unroll 1
  for (int tp = 0; tp < 15; ++tp) { VTILE(0, 1) VTILE(1, 1) }
  VTILE(0, 1)  // t=30 (stages tile 31)
  VTILE(1, 0)  // t=31

  // epilogue: scatter Q/K/V (block-uniform which; n-tile never straddles boundaries)
  const int which = n0 >> 10;
#pragma unroll
  for (int nb = 0; nb < 4; ++nb) {
    const int n = n0 + w * 64 + nb * 16 + fr;
    const float bs = bias[n];
    const int c = n & 1023, h = c >> 6, hd = c & 63;
#pragma unroll
    for (int mb = 0; mb < 8; ++mb) {
      const int mbase = m0 + mb * 16 + fg * 4;
      const int bb = mbase >> 11;
      const int tt = mbase & 2047;
      if (which == 0) {
        u16* dst = Qo + ((size_t)(bb * 16 + h) * 2048 + tt) * 64 + hd;
#pragma unroll
        for (int r = 0; r < 4; ++r) dst[(size_t)r * 64] = f2bf((acc[mb][nb][r] + bs) * 0.125f);
      } else if (which == 1) {
        u16* dst = Ko + ((size_t)(bb * 16 + h) * 2048 + tt) * 64 + hd;
#pragma unroll
        for (int r = 0; r < 4; ++r) dst[(size_t)r * 64] = f2bf(acc[mb][nb][r] + bs);
      } else {
        ushort4 pv;
        pv.x = f2bf(acc[mb][nb][0] + bs);
        pv.y = f2bf(acc[mb][nb][1] + bs);
        pv.z = f2bf(acc[mb][nb][2] + bs);
        pv.w = f2bf(acc[mb][nb][3] + bs);
        *(ushort4*)(Vt + ((size_t)(bb * 16 + h) * 64 + hd) * 2048 + tt) = pv;
      }
    }
  }
#undef VSTGA
#undef VSTGB
#undef VTILE
}

// ---------------- Proj GEMM: 128x128 tile, BK=32, co-resident (target 4 waves/SIMD) ----------------
__global__ __launch_bounds__(256, 4) void gemm_proj_v2(const u16* __restrict__ A,
                                                       const u16* __restrict__ Bt,
                                                       const float* __restrict__ bias,
                                                       float* __restrict__ O) {
  __shared__ u16 sm[2][8192];  // per buf: A [0,4096) = [128][32], B [4096,8192) = [128][32]
  const int bid = blockIdx.x;
  const int swz = (bid & 7) * 64 + (bid >> 3);  // 512 % 8 == 0 -> bijective
  const int m0 = (swz >> 3) * 128, n0 = (swz & 7) * 128;
  GEMM_LANE_CONSTS

  const u16* gA = A + (size_t)(m0 + srow) * 1024 + scol;
  const u16* gB = Bt + (size_t)(n0 + srow) * 1024 + scol;

#define PSTGA(D, C) gload_lds16(gA + (size_t)(C) * 65536, &sm[(D)][(C) * 2048 + tid * 8])
#define PSTGB(D, C) gload_lds16(gB + (size_t)(C) * 65536, &sm[(D)][4096 + (C) * 2048 + tid * 8])

  f32x4 acc[8][2];
#pragma unroll
  for (int i = 0; i < 8; ++i)
#pragma unroll
    for (int j = 0; j < 2; ++j) acc[i][j] = (f32x4){0, 0, 0, 0};

  PSTGA(0, 0); PSTGA(0, 1);
  PSTGB(0, 0); PSTGB(0, 1);
  gA += 32; gB += 32;
  __syncthreads();

  const int aoff = fr * 32 + ((fg * 8) ^ swS);
  const int boff = 4096 + w * 1024 + fr * 32 + ((fg * 8) ^ swS);

#define PTILE(B_, S_)                                                          \
  {                                                                            \
    if (S_) { PSTGA((B_) ^ 1, 0); PSTGA((B_) ^ 1, 1);                          \
              PSTGB((B_) ^ 1, 0); PSTGB((B_) ^ 1, 1); }                        \
    bf16x8 av[4], bv[2];                                                       \
    _Pragma("unroll") for (int nb = 0; nb < 2; ++nb)                           \
        bv[nb] = *(const bf16x8*)&sm[(B_)][boff + nb * 512];                   \
    _Pragma("unroll") for (int i = 0; i < 4; ++i)                              \
        av[i] = *(const bf16x8*)&sm[(B_)][aoff + i * 512];                     \
    _Pragma("unroll") for (int i = 0; i < 4; ++i)                              \
        _Pragma("unroll") for (int nb = 0; nb < 2; ++nb)                       \
            acc[i][nb] = MFMA16(av[i], bv[nb], acc[i][nb]);                    \
    _Pragma("unroll") for (int i = 0; i < 4; ++i)                              \
        av[i] = *(const bf16x8*)&sm[(B_)][aoff + (4 + i) * 512];               \
    _Pragma("unroll") for (int i = 0; i < 4; ++i)                              \
        _Pragma("unroll") for (int nb = 0; nb < 2; ++nb)                       \
            acc[4 + i][nb] = MFMA16(av[i], bv[nb], acc[4 + i][nb]);            \
    if (S_) { gA += 32; gB += 32; }                                            \
    __syncthreads();                                                           \
  }

#pragma unroll 1
  for (int tp = 0; tp < 15; ++tp) { PTILE(0, 1) PTILE(1, 1) }
  PTILE(0, 1)  // t=30 (stages tile 31)
  PTILE(1, 0)  // t=31

  // epilogue: classic C/D layout (col = fr -> n, row = fg*4+r -> m)
#pragma unroll
  for (int nb = 0; nb < 2; ++nb) {
    const int n = n0 + w * 32 + nb * 16 + fr;
    const float bs = bias[n];
#pragma unroll
    for (int mb = 0; mb < 8; ++mb) {
      const int tg = m0 + mb * 16 + fg * 4;
#pragma unroll
      for (int r = 0; r < 4; ++r) O[(size_t)(tg + r) * 1024 + n] = acc[mb][nb][r] + bs;
    }
  }
#undef PSTGA
#undef PSTGB
#undef PTILE
}

// ---------------- Flash attention (R4/v4 form, measured best): 128 q/block (32/wave) ----------------
// S^T = K·Q^T (no max pass), O^T = V^T·P^T. PSTR=72 -> 36.9 KB LDS -> 4 blocks/CU.
#define PSTR 72
__global__ __launch_bounds__(256) void attn_k(const u16* __restrict__ Q,
                                              const u16* __restrict__ Kb,
                                              const u16* __restrict__ Vt,
                                              u16* __restrict__ Y) {
  __shared__ u16 Ks[64 * 72];
  __shared__ u16 Vs[64 * 72];
  __shared__ u16 Ps[4 * 32 * PSTR];
  const int L = blockIdx.x;
  const int xcd = L & 7, slot = L >> 3;
  const int bh = xcd * 8 + (slot & 7);
  const int qt = 15 - (slot >> 3);
  const int tid = threadIdx.x, w = tid >> 6, lane = tid & 63;
  const int fr = lane & 15, fg = lane >> 4;
  const u16* Qp = Q + (size_t)bh * 2048 * 64;
  const u16* Kp = Kb + (size_t)bh * 2048 * 64;
  const u16* Vp = Vt + (size_t)bh * 64 * 2048;
  const int qw = qt * 128 + w * 32;

  bf16x8 qa[2][2];
#pragma unroll
  for (int g = 0; g < 2; ++g)
#pragma unroll
    for (int c = 0; c < 2; ++c)
      qa[g][c] = *(const bf16x8*)(Qp + (size_t)(qw + g * 16 + fr) * 64 + c * 32 + fg * 8);

  float li[2] = {0.f, 0.f};
  f32x4 ot[2][4];
#pragma unroll
  for (int g = 0; g < 2; ++g)
#pragma unroll
    for (int mb = 0; mb < 4; ++mb) ot[g][mb] = (f32x4){0, 0, 0, 0};

  const int srow = tid >> 2, scol = (tid & 3) * 16;
  u16* Pw = Ps + w * 32 * PSTR;
  const int nk = 2 * qt + 2;
  const u16* Kg = Kp + (size_t)srow * 64 + scol;
  const u16* Vg = Vp + (size_t)srow * 2048 + scol;

  uint4 kr0 = *(const uint4*)(Kg);
  uint4 kr1 = *(const uint4*)(Kg + 8);
  uint4 vr0 = *(const uint4*)(Vg);
  uint4 vr1 = *(const uint4*)(Vg + 8);

  for (int jt = 0; jt < nk; ++jt) {
    const int k0 = jt * 64;
    if (jt) __syncthreads();
    *(uint4*)&Ks[srow * 72 + scol] = kr0;
    *(uint4*)&Ks[srow * 72 + scol + 8] = kr1;
    *(uint4*)&Vs[srow * 72 + scol] = vr0;
    *(uint4*)&Vs[srow * 72 + scol + 8] = vr1;
    __syncthreads();
    if (jt + 1 < nk) {
      const int kn = (jt + 1) * 64;
      kr0 = *(const uint4*)(Kg + (size_t)kn * 64);
      kr1 = *(const uint4*)(Kg + (size_t)kn * 64 + 8);
      vr0 = *(const uint4*)(Vg + kn);
      vr1 = *(const uint4*)(Vg + kn + 8);
    }
    if (k0 > qw + 31) continue;

    bf16x8 kb[4][2];
#pragma unroll
    for (int nb = 0; nb < 4; ++nb) {
      kb[nb][0] = *(const bf16x8*)&Ks[(nb * 16 + fr) * 72 + fg * 8];
      kb[nb][1] = *(const bf16x8*)&Ks[(nb * 16 + fr) * 72 + 32 + fg * 8];
    }
    f32x4 st[2][4];
#pragma unroll
    for (int g = 0; g < 2; ++g)
#pragma unroll
      for (int nb = 0; nb < 4; ++nb) {
        f32x4 z = (f32x4){0, 0, 0, 0};
        z = MFMA16(kb[nb][0], qa[g][0], z);
        z = MFMA16(kb[nb][1], qa[g][1], z);
        st[g][nb] = z;
      }
    const bool needmask = (k0 + 63 > qw);
#pragma unroll
    for (int g = 0; g < 2; ++g) {
      const int q = qw + g * 16 + fr;
      float rs0 = 0.f, rs1 = 0.f;
#pragma unroll
      for (int nb = 0; nb < 4; ++nb) {
        const int kcb = k0 + nb * 16 + 4 * fg;
        float p0 = __expf(st[g][nb][0]);
        float p1 = __expf(st[g][nb][1]);
        float p2 = __expf(st[g][nb][2]);
        float p3 = __expf(st[g][nb][3]);
        if (needmask) {
          p0 = (kcb + 0 > q) ? 0.f : p0;
          p1 = (kcb + 1 > q) ? 0.f : p1;
          p2 = (kcb + 2 > q) ? 0.f : p2;
          p3 = (kcb + 3 > q) ? 0.f : p3;
        }
        rs0 += p0 + p1;
        rs1 += p2 + p3;
        *(uint2*)&Pw[(g * 16 + fr) * PSTR + nb * 16 + 4 * fg] =
            make_uint2(pk_trunc(p1, p0), pk_trunc(p3, p2));
      }
      li[g] += rs0 + rs1;
    }
    bf16x8 pa[2][2];
#pragma unroll
    for (int g = 0; g < 2; ++g)
#pragma unroll
      for (int H = 0; H < 2; ++H)
        pa[g][H] = *(const bf16x8*)&Pw[(g * 16 + fr) * PSTR + H * 32 + fg * 8];
#pragma unroll
    for (int mb = 0; mb < 4; ++mb) {
      bf16x8 vb0 = *(const bf16x8*)&Vs[(mb * 16 + fr) * 72 + fg * 8];
      bf16x8 vb1 = *(const bf16x8*)&Vs[(mb * 16 + fr) * 72 + 32 + fg * 8];
#pragma unroll
      for (int g = 0; g < 2; ++g) {
        ot[g][mb] = MFMA16(vb0, pa[g][0], ot[g][mb]);
        ot[g][mb] = MFMA16(vb1, pa[g][1], ot[g][mb]);
      }
    }
  }

  const int b = bh >> 4, h = bh & 15;
#pragma unroll
  for (int g = 0; g < 2; ++g) {
    float l = li[g];
    l += __shfl_xor(l, 16);
    l += __shfl_xor(l, 32);
    const float inv = 1.0f / l;
    const int t = qw + g * 16 + fr;
    u16* yrow = Y + ((size_t)b * 2048 + t) * 1024 + h * 64;
#pragma unroll
    for (int mb = 0; mb < 4; ++mb) {
      const unsigned d0 = (unsigned)f2bf(ot[g][mb][0] * inv) |
                          ((unsigned)f2bf(ot[g][mb][1] * inv) << 16);
      const unsigned d1 = (unsigned)f2bf(ot[g][mb][2] * inv) |
                          ((unsigned)f2bf(ot[g][mb][3] * inv) << 16);
      *(uint2*)&yrow[mb * 16 + fg * 4] = make_uint2(d0, d1);
    }
  }
}

extern "C" void kernel_launch(void* const* d_in, const int* in_sizes, int n_in,
                              void* d_out, int out_size, void* d_ws, size_t ws_size,
                              hipStream_t stream) {
  const float* x = (const float*)d_in[0];
  const float* Wa = (const float*)d_in[1];
  const float* ba = (const float*)d_in[2];
  const float* Wp = (const float*)d_in[3];
  const float* bp = (const float*)d_in[4];
  float* out = (float*)d_out;

  char* p = (char*)d_ws;
  u16* xb = (u16*)p;   p += (size_t)8192 * 1024 * 2;
  u16* WaT = (u16*)p;  p += (size_t)3072 * 1024 * 2;
  u16* WpT = (u16*)p;  p += (size_t)1024 * 1024 * 2;
  u16* Qb = (u16*)p;   p += (size_t)64 * 2048 * 64 * 2;
  u16* Kbuf = (u16*)p; p += (size_t)64 * 2048 * 64 * 2;
  u16* Vtb = (u16*)p;  p += (size_t)64 * 64 * 2048 * 2;
  u16* Yb = (u16*)p;   p += (size_t)8192 * 1024 * 2;

  convert_bf16_k<<<4096, 256, 0, stream>>>(x, xb, 8192 * 1024);
  transpose2_k<<<1024, 256, 0, stream>>>(Wa, WaT, Wp, WpT);
  gemm_qkv_v2<<<768, 256, 0, stream>>>(xb, WaT, ba, Qb, Kbuf, Vtb);
  attn_k<<<1024, 256, 0, stream>>>(Qb, Kbuf, Vtb, Yb);
  gemm_proj_v2<<<512, 256, 0, stream>>>(Yb, WpT, bp, out);
}